// Round 4
// baseline (820.369 us; speedup 1.0000x reference)
//
#include <hip/hip_runtime.h>
#include <math.h>

// Problem constants (from reference)
#define N_NODES 50000
#define IN_DIM  128
#define HIDDEN  64
#define OUT_DIM 10
#define HEADS   4
#define E_RAW   800000
#define E_TOT   (E_RAW + N_NODES)   // with self-loops: 850000
#define NEG_SLOPE 0.2f

#define NB_SCAN 196   // ceil(50000/256)
#define NB_EDGE 3321  // ceil(850000/256)

// ---------------- edge_index dtype detection ----------------
// Reference creates edge_index as int64; harness convention may deliver int32.
// If the buffer is int64 (little-endian), every odd int32 word is a high word
// of a value < 50000 -> 0. If int32, odd words are random node ids in
// [0, 50000) -> P(all 256 samples zero) ~ (2e-5)^256 ~ 0.
// flag[0] == 1  =>  int32 layout (shift 0);  flag[0] == 0  =>  int64 (shift 1).
__global__ void detect_i32(const int* __restrict__ ei, int* __restrict__ flag) {
    int t = threadIdx.x;                      // single block of 256
    int idx = 2 * (t * 3100 + 17) + 1;        // odd, < 1.6M for t < 256
    if (ei[idx] != 0) atomicOr(flag, 1);
}

// ---------------- CSR build ----------------

__global__ void zero_counts(int* __restrict__ counts, int* __restrict__ flag) {
    int i = blockIdx.x * 256 + threadIdx.x;
    if (i < N_NODES) counts[i] = 0;
    if (i == 0) flag[0] = 0;
}

__global__ void count_edges(const int* __restrict__ ei, int* __restrict__ counts,
                            const int* __restrict__ flag) {
    int t = blockIdx.x * 256 + threadIdx.x;
    if (t >= E_TOT) return;
    int sh = flag[0] ? 0 : 1;                 // int32 -> 0, int64 -> 1 (low word)
    int dst = (t < E_RAW) ? ei[(E_RAW + t) << sh] : (t - E_RAW);
    atomicAdd(&counts[dst], 1);
}

__global__ void scan1(const int* __restrict__ counts, int* __restrict__ indptr,
                      int* __restrict__ bsums) {
    __shared__ int sd[256];
    int t = threadIdx.x;
    int i = blockIdx.x * 256 + t;
    int v = (i < N_NODES) ? counts[i] : 0;
    sd[t] = v;
    __syncthreads();
    for (int o = 1; o < 256; o <<= 1) {
        int x = (t >= o) ? sd[t - o] : 0;
        __syncthreads();
        sd[t] += x;
        __syncthreads();
    }
    int incl = sd[t];
    if (i < N_NODES) indptr[i] = incl - v;   // block-local exclusive
    if (t == 255) bsums[blockIdx.x] = incl;  // block total
}

__global__ void scan2(int* __restrict__ bsums) {
    __shared__ int sd[256];
    int t = threadIdx.x;
    int v = (t < NB_SCAN) ? bsums[t] : 0;
    sd[t] = v;
    __syncthreads();
    for (int o = 1; o < 256; o <<= 1) {
        int x = (t >= o) ? sd[t - o] : 0;
        __syncthreads();
        sd[t] += x;
        __syncthreads();
    }
    if (t < NB_SCAN) bsums[t] = sd[t] - v;   // exclusive block offsets
}

__global__ void scan3(int* __restrict__ indptr, const int* __restrict__ bsums,
                      int* __restrict__ cursor) {
    int i = blockIdx.x * 256 + threadIdx.x;
    if (i < N_NODES) {
        int v = indptr[i] + bsums[blockIdx.x];
        indptr[i] = v;
        cursor[i] = v;
    }
    if (i == 0) indptr[N_NODES] = E_TOT;
}

__global__ void fill_edges(const int* __restrict__ ei, int* __restrict__ cursor,
                           int* __restrict__ esrc, const int* __restrict__ flag) {
    int t = blockIdx.x * 256 + threadIdx.x;
    if (t >= E_TOT) return;
    int sh = flag[0] ? 0 : 1;
    int src, dst;
    if (t < E_RAW) { src = ei[t << sh]; dst = ei[(E_RAW + t) << sh]; }
    else           { src = t - E_RAW; dst = src; }
    int pos = atomicAdd(&cursor[dst], 1);
    esrc[pos] = src;
}

// ---------------- GEMM + attention logits ----------------
// h[n, 256] = X[n, :K] @ W[:K, 256];  AL[n, 0..3] = sum_d h[n,hd,d]*asrc[hd,d],
// AL[n, 4..7] = same with adst. Block: 256 threads = 4 waves; wave w == head w
// (column t -> head t>>6, dim t&63), so the head dot-products are wave reductions.
template <int TM, int K>
__global__ void __launch_bounds__(256) gemm_al(
    const float* __restrict__ X, const float* __restrict__ W,
    const float* __restrict__ asrc, const float* __restrict__ adst,
    float* __restrict__ H, float* __restrict__ AL) {
    __shared__ float xs[TM * K];
    int t = threadIdx.x;
    int n0 = blockIdx.x * TM;

    for (int idx = t; idx < TM * K; idx += 256) {
        int r = idx / K, c = idx % K;   // K is a power of 2 -> shifts
        xs[idx] = X[(n0 + r) * K + c];
    }
    __syncthreads();

    float acc[TM];
#pragma unroll
    for (int i = 0; i < TM; i++) acc[i] = 0.f;

    for (int k = 0; k < K; k++) {
        float w = W[k * 256 + t];
#pragma unroll
        for (int i = 0; i < TM; i++) acc[i] += xs[i * K + k] * w;
    }

    int head = t >> 6, lane = t & 63;
    float a_s = asrc[head * 64 + lane];
    float a_d = adst[head * 64 + lane];
#pragma unroll
    for (int i = 0; i < TM; i++) {
        int n = n0 + i;
        H[n * 256 + t] = acc[i];
        float s = acc[i] * a_s;
        float d = acc[i] * a_d;
#pragma unroll
        for (int o = 32; o > 0; o >>= 1) {
            s += __shfl_down(s, o, 64);
            d += __shfl_down(d, o, 64);
        }
        if (lane == 0) {
            AL[n * 8 + head] = s;
            AL[n * 8 + 4 + head] = d;
        }
    }
}

// ---------------- Per-destination softmax + aggregation ----------------
// One wave per dst node. Pass 1: lane-parallel max of leaky_relu logits.
// Pass 2: edge-serial; all lanes share ex_h; lane owns output dim = lane.
__global__ void __launch_bounds__(256) aggregate(
    const float* __restrict__ H, const float* __restrict__ AL,
    const int* __restrict__ indptr, const int* __restrict__ esrc,
    const float* __restrict__ bias, float* __restrict__ XOUT) {
    int wave = threadIdx.x >> 6, lane = threadIdx.x & 63;
    int n = blockIdx.x * 4 + wave;   // 12500 * 4 == 50000 exactly

    int start = indptr[n], end = indptr[n + 1];
    float4 ald = *(const float4*)(AL + n * 8 + 4);

    // pass 1: per-head max over incoming edges
    float m0 = -1e30f, m1 = -1e30f, m2 = -1e30f, m3 = -1e30f;
    for (int i = start + lane; i < end; i += 64) {
        int s = esrc[i];
        float4 as = *(const float4*)(AL + s * 8);
        float v0 = as.x + ald.x; v0 = v0 > 0.f ? v0 : NEG_SLOPE * v0;
        float v1 = as.y + ald.y; v1 = v1 > 0.f ? v1 : NEG_SLOPE * v1;
        float v2 = as.z + ald.z; v2 = v2 > 0.f ? v2 : NEG_SLOPE * v2;
        float v3 = as.w + ald.w; v3 = v3 > 0.f ? v3 : NEG_SLOPE * v3;
        m0 = fmaxf(m0, v0); m1 = fmaxf(m1, v1);
        m2 = fmaxf(m2, v2); m3 = fmaxf(m3, v3);
    }
#pragma unroll
    for (int o = 1; o < 64; o <<= 1) {
        m0 = fmaxf(m0, __shfl_xor(m0, o, 64));
        m1 = fmaxf(m1, __shfl_xor(m1, o, 64));
        m2 = fmaxf(m2, __shfl_xor(m2, o, 64));
        m3 = fmaxf(m3, __shfl_xor(m3, o, 64));
    }

    // pass 2: exp, denom, weighted accumulate (lane owns dim = lane)
    float d0 = 0.f, d1 = 0.f, d2 = 0.f, d3 = 0.f;
    float a0 = 0.f, a1 = 0.f, a2 = 0.f, a3 = 0.f;

    int i = start;
    int s_nxt = esrc[i];                       // deg >= 1 (self-loop)
    float4 al_nxt = *(const float4*)(AL + s_nxt * 8);
    while (i < end) {
        int s = s_nxt;
        float4 as = al_nxt;
        int j = i + 1;
        if (j < end) {
            s_nxt = esrc[j];
            al_nxt = *(const float4*)(AL + s_nxt * 8);
        }
        float v0 = as.x + ald.x; v0 = v0 > 0.f ? v0 : NEG_SLOPE * v0;
        float v1 = as.y + ald.y; v1 = v1 > 0.f ? v1 : NEG_SLOPE * v1;
        float v2 = as.z + ald.z; v2 = v2 > 0.f ? v2 : NEG_SLOPE * v2;
        float v3 = as.w + ald.w; v3 = v3 > 0.f ? v3 : NEG_SLOPE * v3;
        float e0 = __expf(v0 - m0); float e1 = __expf(v1 - m1);
        float e2 = __expf(v2 - m2); float e3 = __expf(v3 - m3);
        d0 += e0; d1 += e1; d2 += e2; d3 += e3;
        const float* hp = H + s * 256 + lane;
        a0 += e0 * hp[0];
        a1 += e1 * hp[64];
        a2 += e2 * hp[128];
        a3 += e3 * hp[192];
        i = j;
    }

    float r = a0 / d0 + a1 / d1 + a2 / d2 + a3 / d3;
    r = 0.25f * r + bias[lane];
    r = r > 0.f ? r : (__expf(r) - 1.f);   // ELU
    XOUT[n * 64 + lane] = r;
}

// ---------------- Final FC ----------------
__global__ void __launch_bounds__(256) fc_kernel(
    const float* __restrict__ X, const float* __restrict__ fcW,
    const float* __restrict__ fcb, float* __restrict__ OUT) {
    __shared__ float ws[64 * 10];
    __shared__ float bs[10];
    int t = threadIdx.x;
    // BUGFIX (round 4): fcW has 640 elements but blockDim is 256 —
    // the previous `if (t < 640) ws[t] = fcW[t];` left ws[256..639]
    // uninitialized LDS, corrupting 38 of 64 hidden dims for every node.
    for (int i = t; i < 640; i += 256) ws[i] = fcW[i];
    if (t < 10) bs[t] = fcb[t];
    __syncthreads();
    int n = blockIdx.x * 256 + t;
    if (n >= N_NODES) return;
    float acc[10];
#pragma unroll
    for (int c = 0; c < 10; c++) acc[c] = bs[c];
    for (int d = 0; d < 64; d++) {
        float x = X[n * 64 + d];
#pragma unroll
        for (int c = 0; c < 10; c++) acc[c] += x * ws[d * 10 + c];
    }
#pragma unroll
    for (int c = 0; c < 10; c++) OUT[n * 10 + c] = acc[c];
}

// ---------------- Launch ----------------
extern "C" void kernel_launch(void* const* d_in, const int* in_sizes, int n_in,
                              void* d_out, int out_size, void* d_ws, size_t ws_size,
                              hipStream_t stream) {
    const float* x     = (const float*)d_in[0];
    const int*   ei    = (const int*)d_in[1];
    const float* W[3]    = {(const float*)d_in[2], (const float*)d_in[6], (const float*)d_in[10]};
    const float* asrc[3] = {(const float*)d_in[3], (const float*)d_in[7], (const float*)d_in[11]};
    const float* adst[3] = {(const float*)d_in[4], (const float*)d_in[8], (const float*)d_in[12]};
    const float* bias[3] = {(const float*)d_in[5], (const float*)d_in[9], (const float*)d_in[13]};
    const float* fcW = (const float*)d_in[14];
    const float* fcb = (const float*)d_in[15];
    float* out = (float*)d_out;

    char* ws = (char*)d_ws;
    size_t off = 0;
    auto alloc = [&](size_t bytes) {
        void* p = ws + off;
        off = (off + bytes + 255) & ~(size_t)255;
        return p;
    };
    float* H      = (float*)alloc((size_t)N_NODES * 256 * 4);   // 51.2 MB
    float* AL     = (float*)alloc((size_t)N_NODES * 8 * 4);     // 1.6 MB
    float* XA     = (float*)alloc((size_t)N_NODES * 64 * 4);    // 12.8 MB
    float* XB     = (float*)alloc((size_t)N_NODES * 64 * 4);    // 12.8 MB
    int*   counts = (int*)alloc((size_t)N_NODES * 4);
    int*   indptr = (int*)alloc((size_t)(N_NODES + 1) * 4);
    int*   cursor = (int*)alloc((size_t)N_NODES * 4);
    int*   esrc   = (int*)alloc((size_t)E_TOT * 4);             // 3.4 MB
    int*   bsums  = (int*)alloc(256 * 4);
    int*   flag   = (int*)alloc(256 * 4);

    // CSR build (graph is identical each call; ws is re-poisoned so rebuild)
    zero_counts<<<NB_SCAN, 256, 0, stream>>>(counts, flag);
    detect_i32<<<1, 256, 0, stream>>>(ei, flag);
    count_edges<<<NB_EDGE, 256, 0, stream>>>(ei, counts, flag);
    scan1<<<NB_SCAN, 256, 0, stream>>>(counts, indptr, bsums);
    scan2<<<1, 256, 0, stream>>>(bsums);
    scan3<<<NB_SCAN, 256, 0, stream>>>(indptr, bsums, cursor);
    fill_edges<<<NB_EDGE, 256, 0, stream>>>(ei, cursor, esrc, flag);

    // Layer 0
    gemm_al<16, 128><<<N_NODES / 16, 256, 0, stream>>>(x, W[0], asrc[0], adst[0], H, AL);
    aggregate<<<N_NODES / 4, 256, 0, stream>>>(H, AL, indptr, esrc, bias[0], XA);
    // Layer 1
    gemm_al<16, 64><<<N_NODES / 16, 256, 0, stream>>>(XA, W[1], asrc[1], adst[1], H, AL);
    aggregate<<<N_NODES / 4, 256, 0, stream>>>(H, AL, indptr, esrc, bias[1], XB);
    // Layer 2
    gemm_al<16, 64><<<N_NODES / 16, 256, 0, stream>>>(XB, W[2], asrc[2], adst[2], H, AL);
    aggregate<<<N_NODES / 4, 256, 0, stream>>>(H, AL, indptr, esrc, bias[2], XA);

    // Final FC
    fc_kernel<<<NB_SCAN, 256, 0, stream>>>(XA, fcW, fcb, out);
}

// Round 5
// 779.651 us; speedup vs baseline: 1.0522x; 1.0522x over previous
//
#include <hip/hip_runtime.h>
#include <math.h>

// Problem constants (from reference)
#define N_NODES 50000
#define IN_DIM  128
#define HIDDEN  64
#define OUT_DIM 10
#define HEADS   4
#define E_RAW   800000
#define E_TOT   (E_RAW + N_NODES)   // with self-loops: 850000
#define NEG_SLOPE 0.2f

#define NB_SCAN 196   // ceil(50000/256)
#define NB_EDGE 3321  // ceil(850000/256)

// ---------------- edge_index dtype detection ----------------
// flag[0] == 1  =>  int32 layout (shift 0);  flag[0] == 0  =>  int64 (shift 1).
__global__ void detect_i32(const int* __restrict__ ei, int* __restrict__ flag) {
    int t = threadIdx.x;                      // single block of 256
    int idx = 2 * (t * 3100 + 17) + 1;        // odd, < 1.6M for t < 256
    if (ei[idx] != 0) atomicOr(flag, 1);
}

// ---------------- CSR build ----------------

__global__ void zero_counts(int* __restrict__ counts, int* __restrict__ flag) {
    int i = blockIdx.x * 256 + threadIdx.x;
    if (i < N_NODES) counts[i] = 0;
    if (i == 0) flag[0] = 0;
}

__global__ void count_edges(const int* __restrict__ ei, int* __restrict__ counts,
                            const int* __restrict__ flag) {
    int t = blockIdx.x * 256 + threadIdx.x;
    if (t >= E_TOT) return;
    int sh = flag[0] ? 0 : 1;                 // int32 -> 0, int64 -> 1 (low word)
    int dst = (t < E_RAW) ? ei[(E_RAW + t) << sh] : (t - E_RAW);
    atomicAdd(&counts[dst], 1);
}

__global__ void scan1(const int* __restrict__ counts, int* __restrict__ indptr,
                      int* __restrict__ bsums) {
    __shared__ int sd[256];
    int t = threadIdx.x;
    int i = blockIdx.x * 256 + t;
    int v = (i < N_NODES) ? counts[i] : 0;
    sd[t] = v;
    __syncthreads();
    for (int o = 1; o < 256; o <<= 1) {
        int x = (t >= o) ? sd[t - o] : 0;
        __syncthreads();
        sd[t] += x;
        __syncthreads();
    }
    int incl = sd[t];
    if (i < N_NODES) indptr[i] = incl - v;   // block-local exclusive
    if (t == 255) bsums[blockIdx.x] = incl;  // block total
}

__global__ void scan2(int* __restrict__ bsums) {
    __shared__ int sd[256];
    int t = threadIdx.x;
    int v = (t < NB_SCAN) ? bsums[t] : 0;
    sd[t] = v;
    __syncthreads();
    for (int o = 1; o < 256; o <<= 1) {
        int x = (t >= o) ? sd[t - o] : 0;
        __syncthreads();
        sd[t] += x;
        __syncthreads();
    }
    if (t < NB_SCAN) bsums[t] = sd[t] - v;   // exclusive block offsets
}

__global__ void scan3(int* __restrict__ indptr, const int* __restrict__ bsums,
                      int* __restrict__ cursor) {
    int i = blockIdx.x * 256 + threadIdx.x;
    if (i < N_NODES) {
        int v = indptr[i] + bsums[blockIdx.x];
        indptr[i] = v;
        cursor[i] = v;
    }
    if (i == 0) indptr[N_NODES] = E_TOT;
}

__global__ void fill_edges(const int* __restrict__ ei, int* __restrict__ cursor,
                           int* __restrict__ esrc, const int* __restrict__ flag) {
    int t = blockIdx.x * 256 + threadIdx.x;
    if (t >= E_TOT) return;
    int sh = flag[0] ? 0 : 1;
    int src, dst;
    if (t < E_RAW) { src = ei[t << sh]; dst = ei[(E_RAW + t) << sh]; }
    else           { src = t - E_RAW; dst = src; }
    int pos = atomicAdd(&cursor[dst], 1);
    esrc[pos] = src;
}

// ---------------- GEMM + attention logits ----------------
// h[n, col] for col = head*64+dim.  H is stored DIM-MAJOR per node:
// H[n*256 + dim*4 + head]  -> aggregate reads one float4 (4 heads of one dim)
// per lane = a single coalesced dwordx4 per edge.
template <int TM, int K>
__global__ void __launch_bounds__(256) gemm_al(
    const float* __restrict__ X, const float* __restrict__ W,
    const float* __restrict__ asrc, const float* __restrict__ adst,
    float* __restrict__ H, float* __restrict__ AL) {
    __shared__ float xs[TM * K];
    int t = threadIdx.x;
    int n0 = blockIdx.x * TM;

    for (int idx = t; idx < TM * K; idx += 256) {
        int r = idx / K, c = idx % K;   // K is a power of 2 -> shifts
        xs[idx] = X[(n0 + r) * K + c];
    }
    __syncthreads();

    float acc[TM];
#pragma unroll
    for (int i = 0; i < TM; i++) acc[i] = 0.f;

    for (int k = 0; k < K; k++) {
        float w = W[k * 256 + t];
#pragma unroll
        for (int i = 0; i < TM; i++) acc[i] += xs[i * K + k] * w;
    }

    int head = t >> 6, lane = t & 63;
    float a_s = asrc[head * 64 + lane];
    float a_d = adst[head * 64 + lane];
#pragma unroll
    for (int i = 0; i < TM; i++) {
        int n = n0 + i;
        H[n * 256 + lane * 4 + head] = acc[i];   // dim-major layout
        float s = acc[i] * a_s;
        float d = acc[i] * a_d;
#pragma unroll
        for (int o = 32; o > 0; o >>= 1) {
            s += __shfl_down(s, o, 64);
            d += __shfl_down(d, o, 64);
        }
        if (lane == 0) {
            AL[n * 8 + head] = s;
            AL[n * 8 + 4 + head] = d;
        }
    }
}

// ---------------- Per-destination softmax + aggregation ----------------
// One wave per dst node, SINGLE pass (no max subtraction: logits are
// analytically bounded |e| <~ 30 -> exp safe in f32; softmax is
// shift-invariant so the result matches the reference).
// esrc indices are staged 64-at-a-time by the wave and broadcast via shfl;
// next edge's AL/H loads are prefetched one iteration ahead.
// Lane owns dim=lane; the H read per edge is ONE dwordx4 (4 heads of dim).
__global__ void __launch_bounds__(256) aggregate(
    const float* __restrict__ H, const float* __restrict__ AL,
    const int* __restrict__ indptr, const int* __restrict__ esrc,
    const float* __restrict__ bias, float* __restrict__ XOUT) {
    int wave = threadIdx.x >> 6, lane = threadIdx.x & 63;
    int n = blockIdx.x * 4 + wave;   // 12500 * 4 == 50000 exactly

    int start = indptr[n], end = indptr[n + 1];
    float4 ald = *(const float4*)(AL + n * 8 + 4);

    float d0 = 0.f, d1 = 0.f, d2 = 0.f, d3 = 0.f;
    float a0 = 0.f, a1 = 0.f, a2 = 0.f, a3 = 0.f;

    // stage first chunk of edge indices (deg >= 1 via self-loop)
    int cb = start;
    int my_s = (cb + lane < end) ? esrc[cb + lane] : 0;
    int s_a = __shfl(my_s, 0, 64);
    float4 al_a = *(const float4*)(AL + s_a * 8);
    float4 h_a  = *(const float4*)(H + s_a * 256 + lane * 4);

    for (int i = start; i < end; ) {
        int j = i + 1;
        int s_b = s_a; float4 al_b = al_a; float4 h_b = h_a;
        if (j < end) {                      // prefetch edge j (wave-uniform)
            int rel = j - cb;
            if (rel == 64) {                // advance chunk (wave-uniform)
                cb = j;
                my_s = (cb + lane < end) ? esrc[cb + lane] : 0;
                rel = 0;
            }
            s_b  = __shfl(my_s, rel, 64);
            al_b = *(const float4*)(AL + s_b * 8);
            h_b  = *(const float4*)(H + s_b * 256 + lane * 4);
        }
        // compute edge i
        float v0 = al_a.x + ald.x; v0 = v0 > 0.f ? v0 : NEG_SLOPE * v0;
        float v1 = al_a.y + ald.y; v1 = v1 > 0.f ? v1 : NEG_SLOPE * v1;
        float v2 = al_a.z + ald.z; v2 = v2 > 0.f ? v2 : NEG_SLOPE * v2;
        float v3 = al_a.w + ald.w; v3 = v3 > 0.f ? v3 : NEG_SLOPE * v3;
        float e0 = __expf(v0); float e1 = __expf(v1);
        float e2 = __expf(v2); float e3 = __expf(v3);
        d0 += e0; d1 += e1; d2 += e2; d3 += e3;
        a0 += e0 * h_a.x;
        a1 += e1 * h_a.y;
        a2 += e2 * h_a.z;
        a3 += e3 * h_a.w;
        s_a = s_b; al_a = al_b; h_a = h_b; i = j;
    }

    float r = a0 / d0 + a1 / d1 + a2 / d2 + a3 / d3;
    r = 0.25f * r + bias[lane];
    r = r > 0.f ? r : (__expf(r) - 1.f);   // ELU
    XOUT[n * 64 + lane] = r;
}

// ---------------- Final FC ----------------
__global__ void __launch_bounds__(256) fc_kernel(
    const float* __restrict__ X, const float* __restrict__ fcW,
    const float* __restrict__ fcb, float* __restrict__ OUT) {
    __shared__ float ws[64 * 10];
    __shared__ float bs[10];
    int t = threadIdx.x;
    for (int i = t; i < 640; i += 256) ws[i] = fcW[i];   // grid-stride: 640 > blockDim
    if (t < 10) bs[t] = fcb[t];
    __syncthreads();
    int n = blockIdx.x * 256 + t;
    if (n >= N_NODES) return;
    float acc[10];
#pragma unroll
    for (int c = 0; c < 10; c++) acc[c] = bs[c];
    for (int d = 0; d < 64; d++) {
        float x = X[n * 64 + d];
#pragma unroll
        for (int c = 0; c < 10; c++) acc[c] += x * ws[d * 10 + c];
    }
#pragma unroll
    for (int c = 0; c < 10; c++) OUT[n * 10 + c] = acc[c];
}

// ---------------- Launch ----------------
extern "C" void kernel_launch(void* const* d_in, const int* in_sizes, int n_in,
                              void* d_out, int out_size, void* d_ws, size_t ws_size,
                              hipStream_t stream) {
    const float* x     = (const float*)d_in[0];
    const int*   ei    = (const int*)d_in[1];
    const float* W[3]    = {(const float*)d_in[2], (const float*)d_in[6], (const float*)d_in[10]};
    const float* asrc[3] = {(const float*)d_in[3], (const float*)d_in[7], (const float*)d_in[11]};
    const float* adst[3] = {(const float*)d_in[4], (const float*)d_in[8], (const float*)d_in[12]};
    const float* bias[3] = {(const float*)d_in[5], (const float*)d_in[9], (const float*)d_in[13]};
    const float* fcW = (const float*)d_in[14];
    const float* fcb = (const float*)d_in[15];
    float* out = (float*)d_out;

    char* ws = (char*)d_ws;
    size_t off = 0;
    auto alloc = [&](size_t bytes) {
        void* p = ws + off;
        off = (off + bytes + 255) & ~(size_t)255;
        return p;
    };
    float* H      = (float*)alloc((size_t)N_NODES * 256 * 4);   // 51.2 MB
    float* AL     = (float*)alloc((size_t)N_NODES * 8 * 4);     // 1.6 MB
    float* XA     = (float*)alloc((size_t)N_NODES * 64 * 4);    // 12.8 MB
    float* XB     = (float*)alloc((size_t)N_NODES * 64 * 4);    // 12.8 MB
    int*   counts = (int*)alloc((size_t)N_NODES * 4);
    int*   indptr = (int*)alloc((size_t)(N_NODES + 1) * 4);
    int*   cursor = (int*)alloc((size_t)N_NODES * 4);
    int*   esrc   = (int*)alloc((size_t)E_TOT * 4);             // 3.4 MB
    int*   bsums  = (int*)alloc(256 * 4);
    int*   flag   = (int*)alloc(256 * 4);

    // CSR build (graph is identical each call; ws is re-poisoned so rebuild)
    zero_counts<<<NB_SCAN, 256, 0, stream>>>(counts, flag);
    detect_i32<<<1, 256, 0, stream>>>(ei, flag);
    count_edges<<<NB_EDGE, 256, 0, stream>>>(ei, counts, flag);
    scan1<<<NB_SCAN, 256, 0, stream>>>(counts, indptr, bsums);
    scan2<<<1, 256, 0, stream>>>(bsums);
    scan3<<<NB_SCAN, 256, 0, stream>>>(indptr, bsums, cursor);
    fill_edges<<<NB_EDGE, 256, 0, stream>>>(ei, cursor, esrc, flag);

    // Layer 0
    gemm_al<16, 128><<<N_NODES / 16, 256, 0, stream>>>(x, W[0], asrc[0], adst[0], H, AL);
    aggregate<<<N_NODES / 4, 256, 0, stream>>>(H, AL, indptr, esrc, bias[0], XA);
    // Layer 1
    gemm_al<16, 64><<<N_NODES / 16, 256, 0, stream>>>(XA, W[1], asrc[1], adst[1], H, AL);
    aggregate<<<N_NODES / 4, 256, 0, stream>>>(H, AL, indptr, esrc, bias[1], XB);
    // Layer 2
    gemm_al<16, 64><<<N_NODES / 16, 256, 0, stream>>>(XB, W[2], asrc[2], adst[2], H, AL);
    aggregate<<<N_NODES / 4, 256, 0, stream>>>(H, AL, indptr, esrc, bias[2], XA);

    // Final FC
    fc_kernel<<<NB_SCAN, 256, 0, stream>>>(XA, fcW, fcb, out);
}